// Round 9
// baseline (5395.617 us; speedup 1.0000x reference)
//
#include <hip/hip_runtime.h>

#define VOCABSZ 256
#define EMBED   32
#define HIDDEN  32
#define LAYERS  10
#define BATCH   1024
#define SEQ     1024
#define BPB     16      // batch elems per group (= MFMA N)
#define U       4       // timesteps per body
#define DEPTH   4       // ring depth in bodies
#define NBODY   (SEQ / U)       // 256 bodies per wave
#define NBG     (BATCH / BPB)   // 64 batch groups
#define RING_BYTES ((size_t)NBG * (LAYERS - 1) * DEPTH * U * 1024)  // 9,437,184
#define FLAG_BYTES ((size_t)NBG * LAYERS * 16 * sizeof(int))        // 40,960

typedef _Float16 f16x8 __attribute__((ext_vector_type(8)));
typedef float    f32x4 __attribute__((ext_vector_type(4)));
typedef _Float16 h2    __attribute__((ext_vector_type(2)));

__device__ __forceinline__ unsigned pk(float a, float b) {
    h2 t; t[0] = (_Float16)a; t[1] = (_Float16)b;
    return __builtin_bit_cast(unsigned, t);
}
__device__ __forceinline__ f16x8 u2f(uint4 u) { return __builtin_bit_cast(f16x8, u); }

// tanh(c + bias) with bias prefolded: t = c*2log2e + bias2; 1 - 2/(1+2^t).
__device__ __forceinline__ float th(float c, float b2) {
    const float t = __builtin_fmaf(c, 2.8853900817779268f, b2);
#if __has_builtin(__builtin_amdgcn_exp2f)
    const float e = __builtin_amdgcn_exp2f(t);
#else
    const float e = __expf(0.6931471805599453f * t);
#endif
    const float r = __builtin_amdgcn_rcpf(1.0f + e);
    return __builtin_fmaf(-2.0f, r, 1.0f);
}

// A-fragment builders (lane (bc,g) takes 8 cols of its weight row, f16).
// kperm: cols {4g..4g+3, 16+4g..16+4g+3} — kappa ordering so C-fragment
// outputs land in-lane as the next B-fragment (verified rounds 3-8).
__device__ __forceinline__ uint4 mk_nat(const float* row, int g) {
    const float4 a = *(const float4*)(row + 8 * g);
    const float4 b = *(const float4*)(row + 8 * g + 4);
    return uint4{pk(a.x, a.y), pk(a.z, a.w), pk(b.x, b.y), pk(b.z, b.w)};
}
__device__ __forceinline__ uint4 mk_kp(const float* row, int g) {
    const float4 a = *(const float4*)(row + 4 * g);
    const float4 b = *(const float4*)(row + 16 + 4 * g);
    return uint4{pk(a.x, a.y), pk(a.z, a.w), pk(b.x, b.y), pk(b.z, b.w)};
}

__device__ __forceinline__ void rel_fence() {
#if __has_builtin(__builtin_amdgcn_fence)
    __builtin_amdgcn_fence(__ATOMIC_RELEASE, "agent");
#else
    __threadfence();
#endif
}

// ============================================================================
// Cross-CU systolic pipeline: 640 blocks x 64 threads; block (bg,w) = wave w
// (layer w) of batch-group bg. Mapping blk = w*64+bg puts producer/consumer
// pairs 64 apart -> same XCD under round-robin dispatch (L2-local handoff).
// Handoff: DEPTH=4 ring of 1KB h-frags in d_ws + per-wave monotone progress
// flags (agent-scope acquire/release). Each wave owns a SIMD -> full issue BW.
// Poison 0xAA = negative flag -> consumers wait until blocks self-zero: safe.
// ============================================================================
__global__ __launch_bounds__(64) void rnn_sys(
    const int* __restrict__ x, const float* __restrict__ emb,
    const float* __restrict__ W_ih, const float* __restrict__ W_hh,
    const float* __restrict__ b_ih, const float* __restrict__ b_hh,
    const float* __restrict__ W_fc, const float* __restrict__ b_fc,
    float* __restrict__ out, unsigned char* ring, int* flags)
{
    const int w     = blockIdx.x >> 6;   // layer
    const int bg    = blockIdx.x & 63;   // batch group
    const int lane  = threadIdx.x;
    const int bc    = lane & 15;         // batch col
    const int g     = lane >> 4;         // k-group / C row-group
    const int bbase = bg * BPB;

    int* const f_self = flags + (bg * LAYERS + w) * 16;
    int* const f_prev = flags + (bg * LAYERS + (w > 0 ? w - 1 : 0)) * 16;
    int* const f_next = flags + (bg * LAYERS + (w < LAYERS - 1 ? w + 1 : w)) * 16;
    if (lane == 0)
        __hip_atomic_store(f_self, 0, __ATOMIC_RELEASE, __HIP_MEMORY_SCOPE_AGENT);

    // ---- weight A-fragments (kappa-permuted cols; layer-0 W_ih natural)
    const float* ri0 = W_ih + (w * HIDDEN + bc)      * EMBED;
    const float* ri1 = W_ih + (w * HIDDEN + 16 + bc) * EMBED;
    const float* rh0 = W_hh + (w * HIDDEN + bc)      * HIDDEN;
    const float* rh1 = W_hh + (w * HIDDEN + 16 + bc) * HIDDEN;
    const uint4 wf00 = (w == 0) ? mk_nat(ri0, g) : mk_kp(ri0, g);
    const uint4 wf10 = (w == 0) ? mk_nat(ri1, g) : mk_kp(ri1, g);
    const uint4 wf01 = mk_kp(rh0, g);
    const uint4 wf11 = mk_kp(rh1, g);

    float bias2[8];
    #pragma unroll
    for (int m = 0; m < 2; ++m)
        #pragma unroll
        for (int r = 0; r < 4; ++r) {
            const int hid = w * HIDDEN + m * 16 + g * 4 + r;
            bias2[m * 4 + r] = 2.8853900817779268f * (b_ih[hid] + b_hh[hid]);
        }

    // ring frag base: producer layer wp (0..8), slot S, sub-timestep u
    auto rb = [&](int wp, int S, int u) -> unsigned char* {
        return ring + (size_t)((((bg * (LAYERS - 1) + wp) * DEPTH + S) * U + u)) * 1024;
    };
    const int off = g * 256 + bc * 16;   // b128 frag address (write == read image)

    // ---- wave-0 feeder: cur = input frags for this body; tokens 1 body ahead
    uint4  cur[U];
    float4 eraw[U][2];
    int4   tok_pf;
    const int* xp = x + (bbase + bc) * SEQ;
    if (w == 0) {
        const int4 t4 = *(const int4*)(xp);
        const int tk[U] = {t4.x, t4.y, t4.z, t4.w};
        #pragma unroll
        for (int u = 0; u < U; ++u) {
            const float4* ep = (const float4*)(emb + tk[u] * EMBED + g * 8);
            const float4 e0 = ep[0], e1 = ep[1];
            cur[u] = uint4{pk(e0.x, e0.y), pk(e0.z, e0.w), pk(e1.x, e1.y), pk(e1.z, e1.w)};
        }
        tok_pf = *(const int4*)(xp + U);
    }

    uint4 bown = uint4{0, 0, 0, 0};   // own-h B-frag, register-resident forever
    const f32x4 z = {0.f, 0.f, 0.f, 0.f};

    int  Fp = 0, Fn = 0;     // cached neighbor flags ("completed >= 0" vacuously true)
    bool havePre = false;
    uint4 binN[U];

    auto body = [&](int it, int S) {
        const int tb = it * U;
        // ---- acquire inputs for body it (producer body it, slot S)
        uint4 bin[U];
        if (w == 0) {
            #pragma unroll
            for (int u = 0; u < U; ++u) bin[u] = cur[u];
        } else if (havePre) {
            #pragma unroll
            for (int u = 0; u < U; ++u) bin[u] = binN[u];
        } else {
            while (Fp < it + 1) {
                Fp = __hip_atomic_load(f_prev, __ATOMIC_ACQUIRE, __HIP_MEMORY_SCOPE_AGENT);
                if (Fp < it + 1) __builtin_amdgcn_s_sleep(2);
            }
            #pragma unroll
            for (int u = 0; u < U; ++u)
                bin[u] = *(const uint4*)(rb(w - 1, S, u) + off);
        }
        // ---- ring space: slot S previously held body it-DEPTH; consumer must
        //      have finished body it-DEPTH (flag >= it-DEPTH+1)
        if (w < LAYERS - 1) {
            while (Fn < it - (DEPTH - 1)) {
                Fn = __hip_atomic_load(f_next, __ATOMIC_ACQUIRE, __HIP_MEMORY_SCOPE_AGENT);
                if (Fn < it - (DEPTH - 1)) __builtin_amdgcn_s_sleep(2);
            }
        }
        // ---- input MFMAs (off the serial chain)
        f32x4 cin0[U], cin1[U];
        #pragma unroll
        for (int u = 0; u < U; ++u) {
            cin0[u] = __builtin_amdgcn_mfma_f32_16x16x32_f16(u2f(wf00), u2f(bin[u]), z, 0, 0, 0);
            cin1[u] = __builtin_amdgcn_mfma_f32_16x16x32_f16(u2f(wf10), u2f(bin[u]), z, 0, 0, 0);
        }
        // ---- feeder issue (w==0) / next-body input prefetch (w>0); latency
        //      hides under the ~700cy recurrence below
        const bool pf = (w == 0) && (tb + U < SEQ);
        if (pf) {
            const int tk[U] = {tok_pf.x, tok_pf.y, tok_pf.z, tok_pf.w};
            #pragma unroll
            for (int u = 0; u < U; ++u) {
                const float4* ep = (const float4*)(emb + tk[u] * EMBED + g * 8);
                eraw[u][0] = ep[0]; eraw[u][1] = ep[1];
            }
            if (tb + 2 * U < SEQ) tok_pf = *(const int4*)(xp + tb + 2 * U);
        }
        if (w > 0) {
            if (Fp < it + 2)
                Fp = __hip_atomic_load(f_prev, __ATOMIC_ACQUIRE, __HIP_MEMORY_SCOPE_AGENT);
            havePre = (it + 1 < NBODY) && (Fp >= it + 2);
            if (havePre) {
                #pragma unroll
                for (int u = 0; u < U; ++u)
                    binN[u] = *(const uint4*)(rb(w - 1, (S + 1) & (DEPTH - 1), u) + off);
            }
        }
        // ---- serial recurrence: mfma -> tanh -> pack IS the next B-frag
        #pragma unroll
        for (int u = 0; u < U; ++u) {
            const f32x4 c0 = __builtin_amdgcn_mfma_f32_16x16x32_f16(u2f(wf01), u2f(bown), cin0[u], 0, 0, 0);
            const f32x4 c1 = __builtin_amdgcn_mfma_f32_16x16x32_f16(u2f(wf11), u2f(bown), cin1[u], 0, 0, 0);
            float hv[8];
            #pragma unroll
            for (int r = 0; r < 4; ++r) {
                hv[r]     = th(c0[r], bias2[r]);
                hv[4 + r] = th(c1[r], bias2[4 + r]);
            }
            bown = uint4{pk(hv[0], hv[1]), pk(hv[2], hv[3]),
                         pk(hv[4], hv[5]), pk(hv[6], hv[7])};
            if (w < LAYERS - 1)
                *(uint4*)(rb(w, S, u) + off) = bown;
        }
        // ---- publish: all lanes' stores drained+written back, then flag bump
        if (w < LAYERS - 1) rel_fence();
        if (lane == 0)
            __hip_atomic_store(f_self, it + 1, __ATOMIC_RELAXED, __HIP_MEMORY_SCOPE_AGENT);
        if (pf) {
            #pragma unroll
            for (int u = 0; u < U; ++u) {
                const float4 e0 = eraw[u][0], e1 = eraw[u][1];
                cur[u] = uint4{pk(e0.x, e0.y), pk(e0.z, e0.w), pk(e1.x, e1.y), pk(e1.z, e1.w)};
            }
        }
    };

    for (int it = 0; it < NBODY; it += 4) {   // slot index static per call site
        body(it + 0, 0);
        body(it + 1, 1);
        body(it + 2, 2);
        body(it + 3, 3);
    }

    // ---- fused FC: wave 9's final bown IS h_T's B-fragment (single wave)
    if (w == LAYERS - 1) {
        #pragma unroll
        for (int vt = 0; vt < VOCABSZ / 16; ++vt) {
            const uint4 afc = mk_kp(W_fc + (vt * 16 + bc) * HIDDEN, g);
            const f32x4 c = __builtin_amdgcn_mfma_f32_16x16x32_f16(u2f(afc), u2f(bown), z, 0, 0, 0);
            const float4 b4 = *(const float4*)(b_fc + vt * 16 + 4 * g);
            const float4 o  = {c[0] + b4.x, c[1] + b4.y, c[2] + b4.z, c[3] + b4.w};
            *(float4*)(out + (bbase + bc) * VOCABSZ + vt * 16 + 4 * g) = o;
        }
    }
}

// ============================================================================
// Fallback (round-8 kernel, verified): used only if ws_size < ~9.5 MB.
// ============================================================================
#define NB 268
__global__ __launch_bounds__(640, 1) void rnn_fused(
    const int* __restrict__ x, const float* __restrict__ emb,
    const float* __restrict__ W_ih, const float* __restrict__ W_hh,
    const float* __restrict__ b_ih, const float* __restrict__ b_hh,
    const float* __restrict__ W_fc, const float* __restrict__ b_fc,
    float* __restrict__ out)
{
    __shared__ __align__(16) unsigned char hb[DEPTH * (LAYERS - 1) * U * 1024];
    __shared__ __align__(16) unsigned char fcs[1024];
    __shared__ volatile int prog[LAYERS * 16];
    #define PROG(i) prog[(i) * 16]

    const int tid   = threadIdx.x;
    const int w     = tid >> 6;
    const int lane  = tid & 63;
    const int bc    = lane & 15;
    const int g     = lane >> 4;
    const int bbase = blockIdx.x * BPB;

    for (int i = tid; i < (int)sizeof(hb) / 4; i += 640)
        ((unsigned*)hb)[i] = 0u;
    if (tid < LAYERS * 16) prog[tid] = 0;

    const float* ri0 = W_ih + (w * HIDDEN + bc)      * EMBED;
    const float* ri1 = W_ih + (w * HIDDEN + 16 + bc) * EMBED;
    const float* rh0 = W_hh + (w * HIDDEN + bc)      * HIDDEN;
    const float* rh1 = W_hh + (w * HIDDEN + 16 + bc) * HIDDEN;
    const uint4 wf00 = (w == 0) ? mk_nat(ri0, g) : mk_kp(ri0, g);
    const uint4 wf10 = (w == 0) ? mk_nat(ri1, g) : mk_kp(ri1, g);
    const uint4 wf01 = mk_kp(rh0, g);
    const uint4 wf11 = mk_kp(rh1, g);

    float bias2[8];
    #pragma unroll
    for (int m = 0; m < 2; ++m)
        #pragma unroll
        for (int r = 0; r < 4; ++r) {
            const int hid = w * HIDDEN + m * 16 + g * 4 + r;
            bias2[m * 4 + r] = 2.8853900817779268f * (b_ih[hid] + b_hh[hid]);
        }

    #define SL(s, l, u_) ((((s) * (LAYERS - 1) + (l)) * U + (u_)) * 1024)
    const int off = g * 256 + bc * 16;

    uint4  cur[U];
    float4 eraw[U][2];
    int4   tok_pf;
    const int* xp = x + (bbase + bc) * SEQ;
    if (w == 0) {
        const int4 t4 = *(const int4*)(xp);
        const int tk[U] = {t4.x, t4.y, t4.z, t4.w};
        #pragma unroll
        for (int u = 0; u < U; ++u) {
            const float4* ep = (const float4*)(emb + tk[u] * EMBED + g * 8);
            const float4 e0 = ep[0], e1 = ep[1];
            cur[u] = uint4{pk(e0.x, e0.y), pk(e0.z, e0.w), pk(e1.x, e1.y), pk(e1.z, e1.w)};
        }
        tok_pf = *(const int4*)(xp + U);
    }

    uint4 bown = uint4{0, 0, 0, 0};
    const f32x4 z = {0.f, 0.f, 0.f, 0.f};

    __syncthreads();

    auto body = [&](int it, int S) {
        const int tb = (it - w) * U;
        if (tb >= 0 && tb < SEQ) {
            if (w > 0)
                while (PROG(w - 1) < it) __builtin_amdgcn_s_sleep(1);
            if (w < LAYERS - 1)
                while (PROG(w + 1) < it - 2) __builtin_amdgcn_s_sleep(1);
            asm volatile("" ::: "memory");

            const bool pf = (w == 0) && (tb + U < SEQ);
            if (pf) {
                const int tk[U] = {tok_pf.x, tok_pf.y, tok_pf.z, tok_pf.w};
                #pragma unroll
                for (int u = 0; u < U; ++u) {
                    const float4* ep = (const float4*)(emb + tk[u] * EMBED + g * 8);
                    eraw[u][0] = ep[0]; eraw[u][1] = ep[1];
                }
                if (tb + 2 * U < SEQ)
                    tok_pf = *(const int4*)(xp + tb + 2 * U);
            }

            uint4 bin[U];
            if (w == 0) {
                #pragma unroll
                for (int u = 0; u < U; ++u) bin[u] = cur[u];
            } else {
                #pragma unroll
                for (int u = 0; u < U; ++u)
                    bin[u] = *(const uint4*)(hb + SL((S + 3) & 3, w - 1, u) + off);
            }
            f32x4 cin0[U], cin1[U];
            #pragma unroll
            for (int u = 0; u < U; ++u) {
                cin0[u] = __builtin_amdgcn_mfma_f32_16x16x32_f16(u2f(wf00), u2f(bin[u]), z, 0, 0, 0);
                cin1[u] = __builtin_amdgcn_mfma_f32_16x16x32_f16(u2f(wf10), u2f(bin[u]), z, 0, 0, 0);
            }
            #pragma unroll
            for (int u = 0; u < U; ++u) {
                const f32x4 c0 = __builtin_amdgcn_mfma_f32_16x16x32_f16(u2f(wf01), u2f(bown), cin0[u], 0, 0, 0);
                const f32x4 c1 = __builtin_amdgcn_mfma_f32_16x16x32_f16(u2f(wf11), u2f(bown), cin1[u], 0, 0, 0);
                float hv[8];
                #pragma unroll
                for (int r = 0; r < 4; ++r) {
                    hv[r]     = th(c0[r], bias2[r]);
                    hv[4 + r] = th(c1[r], bias2[4 + r]);
                }
                bown = uint4{pk(hv[0], hv[1]), pk(hv[2], hv[3]),
                             pk(hv[4], hv[5]), pk(hv[6], hv[7])};
                if (w < LAYERS - 1)
                    *(uint4*)(hb + SL(S, w, u) + off) = bown;
            }
            asm volatile("s_waitcnt lgkmcnt(0)" ::: "memory");
            if (lane == 0) PROG(w) = it + 1;
            if (pf) {
                #pragma unroll
                for (int u = 0; u < U; ++u) {
                    const float4 e0 = eraw[u][0], e1 = eraw[u][1];
                    cur[u] = uint4{pk(e0.x, e0.y), pk(e0.z, e0.w), pk(e1.x, e1.y), pk(e1.z, e1.w)};
                }
            }
        } else {
            if (lane == 0) PROG(w) = it + 1;
        }
    };

    for (int it = 0; it < NB; it += 4) {
        body(it + 0, 0);
        body(it + 1, 1);
        body(it + 2, 2);
        body(it + 3, 3);
    }
    #undef SL

    if (w == LAYERS - 1) *(uint4*)(fcs + off) = bown;
    __syncthreads();
    const uint4 bfc = *(const uint4*)(fcs + off);
    #pragma unroll
    for (int rep = 0; rep < 2; ++rep) {
        const int vt = w + rep * LAYERS;
        if (vt < VOCABSZ / 16) {
            const uint4 afc = mk_kp(W_fc + (vt * 16 + bc) * HIDDEN, g);
            const f32x4 c = __builtin_amdgcn_mfma_f32_16x16x32_f16(u2f(afc), u2f(bfc), z, 0, 0, 0);
            const float4 b4 = *(const float4*)(b_fc + vt * 16 + 4 * g);
            const float4 o  = {c[0] + b4.x, c[1] + b4.y, c[2] + b4.z, c[3] + b4.w};
            *(float4*)(out + (bbase + bc) * VOCABSZ + vt * 16 + 4 * g) = o;
        }
    }
    #undef PROG
}

extern "C" void kernel_launch(void* const* d_in, const int* in_sizes, int n_in,
                              void* d_out, int out_size, void* d_ws, size_t ws_size,
                              hipStream_t stream) {
    const int*   x    = (const int*)d_in[0];
    const float* emb  = (const float*)d_in[1];
    const float* W_ih = (const float*)d_in[2];
    const float* W_hh = (const float*)d_in[3];
    const float* b_ih = (const float*)d_in[4];
    const float* b_hh = (const float*)d_in[5];
    const float* W_fc = (const float*)d_in[6];
    const float* b_fc = (const float*)d_in[7];
    float* out = (float*)d_out;

    if (ws_size >= RING_BYTES + FLAG_BYTES) {
        unsigned char* ring  = (unsigned char*)d_ws;
        int*           flags = (int*)((unsigned char*)d_ws + RING_BYTES);
        rnn_sys<<<LAYERS * NBG, 64, 0, stream>>>(x, emb, W_ih, W_hh, b_ih, b_hh,
                                                 W_fc, b_fc, out, ring, flags);
    } else {
        rnn_fused<<<BATCH / BPB, 640, 0, stream>>>(x, emb, W_ih, W_hh, b_ih, b_hh,
                                                   W_fc, b_fc, out);
    }
}

// Round 10
// 621.640 us; speedup vs baseline: 8.6796x; 8.6796x over previous
//
#include <hip/hip_runtime.h>

#define VOCABSZ 256
#define EMBED   32
#define HIDDEN  32
#define LAYERS  10
#define BATCH   1024
#define SEQ     1024
#define BPB     16      // batch elems per group (= MFMA N)
#define U       4       // timesteps per body
#define DEPTH   4       // ring depth in bodies
#define NBODY   (SEQ / U)       // 256 bodies per wave
#define NBG     (BATCH / BPB)   // 64 batch groups
#define RING_BYTES ((size_t)NBG * (LAYERS - 1) * DEPTH * U * 1024)  // 9,437,184
#define FLAG_BYTES ((size_t)NBG * LAYERS * 16 * sizeof(int))        // 40,960

typedef _Float16 f16x8 __attribute__((ext_vector_type(8)));
typedef float    f32x4 __attribute__((ext_vector_type(4)));
typedef _Float16 h2    __attribute__((ext_vector_type(2)));
typedef unsigned long long u64;

__device__ __forceinline__ unsigned pk(float a, float b) {
    h2 t; t[0] = (_Float16)a; t[1] = (_Float16)b;
    return __builtin_bit_cast(unsigned, t);
}
__device__ __forceinline__ f16x8 u2f(uint4 u) { return __builtin_bit_cast(f16x8, u); }

// tanh(c + bias) with bias prefolded: t = c*2log2e + bias2; 1 - 2/(1+2^t).
__device__ __forceinline__ float th(float c, float b2) {
    const float t = __builtin_fmaf(c, 2.8853900817779268f, b2);
#if __has_builtin(__builtin_amdgcn_exp2f)
    const float e = __builtin_amdgcn_exp2f(t);
#else
    const float e = __expf(0.6931471805599453f * t);
#endif
    const float r = __builtin_amdgcn_rcpf(1.0f + e);
    return __builtin_fmaf(-2.0f, r, 1.0f);
}

// A-fragment builders (lane (bc,g) takes 8 cols of its weight row, f16).
// kperm: cols {4g..4g+3, 16+4g..16+4g+3} — kappa ordering so C-fragment
// outputs land in-lane as the next B-fragment (verified rounds 3-8).
__device__ __forceinline__ uint4 mk_nat(const float* row, int g) {
    const float4 a = *(const float4*)(row + 8 * g);
    const float4 b = *(const float4*)(row + 8 * g + 4);
    return uint4{pk(a.x, a.y), pk(a.z, a.w), pk(b.x, b.y), pk(b.z, b.w)};
}
__device__ __forceinline__ uint4 mk_kp(const float* row, int g) {
    const float4 a = *(const float4*)(row + 4 * g);
    const float4 b = *(const float4*)(row + 16 + 4 * g);
    return uint4{pk(a.x, a.y), pk(a.z, a.w), pk(b.x, b.y), pk(b.z, b.w)};
}

// Device-coherent (L3-point) data movement. Relaxed agent-scope atomic
// load/store are plain global ops with device-coherence cache bits: they
// bypass the non-coherent per-XCD L2s and NEVER flush anything.
// (Round-9 failure: RELEASE fence per body -> 596 MB of L2 writebacks.)
__device__ __forceinline__ void frag_store(void* p, uint4 v) {
    const u64 lo = ((u64)v.y << 32) | v.x;
    const u64 hi = ((u64)v.w << 32) | v.z;
    __hip_atomic_store((u64*)p + 0, lo, __ATOMIC_RELAXED, __HIP_MEMORY_SCOPE_AGENT);
    __hip_atomic_store((u64*)p + 1, hi, __ATOMIC_RELAXED, __HIP_MEMORY_SCOPE_AGENT);
}
__device__ __forceinline__ uint4 frag_load(const void* p) {
    const u64 lo = __hip_atomic_load((const u64*)p + 0, __ATOMIC_RELAXED, __HIP_MEMORY_SCOPE_AGENT);
    const u64 hi = __hip_atomic_load((const u64*)p + 1, __ATOMIC_RELAXED, __HIP_MEMORY_SCOPE_AGENT);
    return uint4{(unsigned)lo, (unsigned)(lo >> 32), (unsigned)hi, (unsigned)(hi >> 32)};
}

// ============================================================================
// Cross-CU systolic pipeline: 640 blocks x 64 threads; block (w,bg) = layer w
// of batch-group bg. ~2.5 single-wave blocks per CU over all 256 CUs ->
// per-SIMD trans-pipe contention drops 4x vs the 10-wave monolithic block
// (the r6/r8 binding constraint). Handoff ring + flags live at the L3
// coherent point via relaxed agent atomics; producer orders data-before-flag
// with one s_waitcnt vmcnt(0). No fences. Deadlock-free: acyclic (it,w) DAG,
// monotone flags, all 640 one-wave blocks co-resident. Poison 0xAA = negative
// flag -> consumers simply wait until each block self-zeroes: safe.
// ============================================================================
__global__ __launch_bounds__(64, 1) void rnn_sys(
    const int* __restrict__ x, const float* __restrict__ emb,
    const float* __restrict__ W_ih, const float* __restrict__ W_hh,
    const float* __restrict__ b_ih, const float* __restrict__ b_hh,
    const float* __restrict__ W_fc, const float* __restrict__ b_fc,
    float* __restrict__ out, unsigned char* ring, int* flags)
{
    const int w     = blockIdx.x >> 6;   // layer
    const int bg    = blockIdx.x & 63;   // batch group
    const int lane  = threadIdx.x;
    const int bc    = lane & 15;         // batch col
    const int g     = lane >> 4;         // k-group / C row-group
    const int bbase = bg * BPB;

    int* const f_self = flags + (bg * LAYERS + w) * 16;
    int* const f_prev = flags + (bg * LAYERS + (w > 0 ? w - 1 : 0)) * 16;
    int* const f_next = flags + (bg * LAYERS + (w < LAYERS - 1 ? w + 1 : w)) * 16;
    if (lane == 0)
        __hip_atomic_store(f_self, 0, __ATOMIC_RELAXED, __HIP_MEMORY_SCOPE_AGENT);

    // ---- weight A-fragments (kappa-permuted cols; layer-0 W_ih natural)
    const float* ri0 = W_ih + (w * HIDDEN + bc)      * EMBED;
    const float* ri1 = W_ih + (w * HIDDEN + 16 + bc) * EMBED;
    const float* rh0 = W_hh + (w * HIDDEN + bc)      * HIDDEN;
    const float* rh1 = W_hh + (w * HIDDEN + 16 + bc) * HIDDEN;
    const uint4 wf00 = (w == 0) ? mk_nat(ri0, g) : mk_kp(ri0, g);
    const uint4 wf10 = (w == 0) ? mk_nat(ri1, g) : mk_kp(ri1, g);
    const uint4 wf01 = mk_kp(rh0, g);
    const uint4 wf11 = mk_kp(rh1, g);

    float bias2[8];
    #pragma unroll
    for (int m = 0; m < 2; ++m)
        #pragma unroll
        for (int r = 0; r < 4; ++r) {
            const int hid = w * HIDDEN + m * 16 + g * 4 + r;
            bias2[m * 4 + r] = 2.8853900817779268f * (b_ih[hid] + b_hh[hid]);
        }

    // ring frag base: producer layer wp (0..8), slot S, sub-timestep u
    auto rb = [&](int wp, int S, int u) -> unsigned char* {
        return ring + (size_t)((((bg * (LAYERS - 1) + wp) * DEPTH + S) * U + u)) * 1024;
    };
    const int off = g * 256 + bc * 16;   // 16B frag address (write == read image)

    // ---- wave-0 feeder: cur = input frags for this body; tokens 1 body ahead
    uint4  cur[U];
    float4 eraw[U][2];
    int4   tok_pf;
    const int* xp = x + (bbase + bc) * SEQ;
    if (w == 0) {
        const int4 t4 = *(const int4*)(xp);
        const int tk[U] = {t4.x, t4.y, t4.z, t4.w};
        #pragma unroll
        for (int u = 0; u < U; ++u) {
            const float4* ep = (const float4*)(emb + tk[u] * EMBED + g * 8);
            const float4 e0 = ep[0], e1 = ep[1];
            cur[u] = uint4{pk(e0.x, e0.y), pk(e0.z, e0.w), pk(e1.x, e1.y), pk(e1.z, e1.w)};
        }
        tok_pf = *(const int4*)(xp + U);
    }

    uint4 bown = uint4{0, 0, 0, 0};   // own-h B-frag, register-resident forever
    const f32x4 z = {0.f, 0.f, 0.f, 0.f};

    int  Fp = 0, Fn = 0;     // cached neighbor flags ("completed >= 0" vacuous)
    bool havePre = false;
    uint4 binN[U];

    auto body = [&](int it, int S) {
        const int tb = it * U;
        // ---- acquire inputs for body it (producer body it, slot S)
        uint4 bin[U];
        if (w == 0) {
            #pragma unroll
            for (int u = 0; u < U; ++u) bin[u] = cur[u];
        } else if (havePre) {
            #pragma unroll
            for (int u = 0; u < U; ++u) bin[u] = binN[u];
        } else {
            while (Fp < it + 1) {
                Fp = __hip_atomic_load(f_prev, __ATOMIC_RELAXED, __HIP_MEMORY_SCOPE_AGENT);
                if (Fp < it + 1) __builtin_amdgcn_s_sleep(2);
            }
            #pragma unroll
            for (int u = 0; u < U; ++u)
                bin[u] = frag_load(rb(w - 1, S, u) + off);
        }
        // ---- ring space: slot S previously held body it-DEPTH; consumer must
        //      have finished it (flag >= it-DEPTH+1)
        if (w < LAYERS - 1) {
            while (Fn < it - (DEPTH - 1)) {
                Fn = __hip_atomic_load(f_next, __ATOMIC_RELAXED, __HIP_MEMORY_SCOPE_AGENT);
                if (Fn < it - (DEPTH - 1)) __builtin_amdgcn_s_sleep(2);
            }
        }
        // ---- input MFMAs (off the serial chain)
        f32x4 cin0[U], cin1[U];
        #pragma unroll
        for (int u = 0; u < U; ++u) {
            cin0[u] = __builtin_amdgcn_mfma_f32_16x16x32_f16(u2f(wf00), u2f(bin[u]), z, 0, 0, 0);
            cin1[u] = __builtin_amdgcn_mfma_f32_16x16x32_f16(u2f(wf10), u2f(bin[u]), z, 0, 0, 0);
        }
        // ---- feeder issue (w==0) / next-body input prefetch (w>0)
        const bool pf = (w == 0) && (tb + U < SEQ);
        if (pf) {
            const int tk[U] = {tok_pf.x, tok_pf.y, tok_pf.z, tok_pf.w};
            #pragma unroll
            for (int u = 0; u < U; ++u) {
                const float4* ep = (const float4*)(emb + tk[u] * EMBED + g * 8);
                eraw[u][0] = ep[0]; eraw[u][1] = ep[1];
            }
            if (tb + 2 * U < SEQ) tok_pf = *(const int4*)(xp + tb + 2 * U);
        }
        if (w > 0) {
            if (Fp < it + 2)
                Fp = __hip_atomic_load(f_prev, __ATOMIC_RELAXED, __HIP_MEMORY_SCOPE_AGENT);
            havePre = (it + 1 < NBODY) && (Fp >= it + 2);
            if (havePre) {
                #pragma unroll
                for (int u = 0; u < U; ++u)
                    binN[u] = frag_load(rb(w - 1, (S + 1) & (DEPTH - 1), u) + off);
            }
        }
        // ---- serial recurrence: mfma -> tanh -> pack IS the next B-frag
        #pragma unroll
        for (int u = 0; u < U; ++u) {
            const f32x4 c0 = __builtin_amdgcn_mfma_f32_16x16x32_f16(u2f(wf01), u2f(bown), cin0[u], 0, 0, 0);
            const f32x4 c1 = __builtin_amdgcn_mfma_f32_16x16x32_f16(u2f(wf11), u2f(bown), cin1[u], 0, 0, 0);
            float hv[8];
            #pragma unroll
            for (int r = 0; r < 4; ++r) {
                hv[r]     = th(c0[r], bias2[r]);
                hv[4 + r] = th(c1[r], bias2[4 + r]);
            }
            bown = uint4{pk(hv[0], hv[1]), pk(hv[2], hv[3]),
                         pk(hv[4], hv[5]), pk(hv[6], hv[7])};
            if (w < LAYERS - 1)
                frag_store(rb(w, S, u) + off, bown);
        }
        // ---- publish: ring stores complete at the coherent point, then flag.
        //      vmcnt(0) (NOT a fence): waits own stores, flushes nothing.
        asm volatile("s_waitcnt vmcnt(0)" ::: "memory");
        if (lane == 0)
            __hip_atomic_store(f_self, it + 1, __ATOMIC_RELAXED, __HIP_MEMORY_SCOPE_AGENT);
        if (pf) {
            #pragma unroll
            for (int u = 0; u < U; ++u) {
                const float4 e0 = eraw[u][0], e1 = eraw[u][1];
                cur[u] = uint4{pk(e0.x, e0.y), pk(e0.z, e0.w), pk(e1.x, e1.y), pk(e1.z, e1.w)};
            }
        }
    };

    for (int it = 0; it < NBODY; it += 4) {   // slot index static per call site
        body(it + 0, 0);
        body(it + 1, 1);
        body(it + 2, 2);
        body(it + 3, 3);
    }

    // ---- fused FC: wave 9's final bown IS h_T's B-fragment (single wave)
    if (w == LAYERS - 1) {
        #pragma unroll
        for (int vt = 0; vt < VOCABSZ / 16; ++vt) {
            const uint4 afc = mk_kp(W_fc + (vt * 16 + bc) * HIDDEN, g);
            const f32x4 c = __builtin_amdgcn_mfma_f32_16x16x32_f16(u2f(afc), u2f(bown), z, 0, 0, 0);
            const float4 b4 = *(const float4*)(b_fc + vt * 16 + 4 * g);
            const float4 o  = {c[0] + b4.x, c[1] + b4.y, c[2] + b4.z, c[3] + b4.w};
            *(float4*)(out + (bbase + bc) * VOCABSZ + vt * 16 + 4 * g) = o;
        }
    }
}

// ============================================================================
// Fallback (round-8 kernel, verified): used only if ws_size < ~9.5 MB.
// ============================================================================
#define NB 268
__global__ __launch_bounds__(640, 1) void rnn_fused(
    const int* __restrict__ x, const float* __restrict__ emb,
    const float* __restrict__ W_ih, const float* __restrict__ W_hh,
    const float* __restrict__ b_ih, const float* __restrict__ b_hh,
    const float* __restrict__ W_fc, const float* __restrict__ b_fc,
    float* __restrict__ out)
{
    __shared__ __align__(16) unsigned char hb[DEPTH * (LAYERS - 1) * U * 1024];
    __shared__ __align__(16) unsigned char fcs[1024];
    __shared__ volatile int prog[LAYERS * 16];
    #define PROG(i) prog[(i) * 16]

    const int tid   = threadIdx.x;
    const int w     = tid >> 6;
    const int lane  = tid & 63;
    const int bc    = lane & 15;
    const int g     = lane >> 4;
    const int bbase = blockIdx.x * BPB;

    for (int i = tid; i < (int)sizeof(hb) / 4; i += 640)
        ((unsigned*)hb)[i] = 0u;
    if (tid < LAYERS * 16) prog[tid] = 0;

    const float* ri0 = W_ih + (w * HIDDEN + bc)      * EMBED;
    const float* ri1 = W_ih + (w * HIDDEN + 16 + bc) * EMBED;
    const float* rh0 = W_hh + (w * HIDDEN + bc)      * HIDDEN;
    const float* rh1 = W_hh + (w * HIDDEN + 16 + bc) * HIDDEN;
    const uint4 wf00 = (w == 0) ? mk_nat(ri0, g) : mk_kp(ri0, g);
    const uint4 wf10 = (w == 0) ? mk_nat(ri1, g) : mk_kp(ri1, g);
    const uint4 wf01 = mk_kp(rh0, g);
    const uint4 wf11 = mk_kp(rh1, g);

    float bias2[8];
    #pragma unroll
    for (int m = 0; m < 2; ++m)
        #pragma unroll
        for (int r = 0; r < 4; ++r) {
            const int hid = w * HIDDEN + m * 16 + g * 4 + r;
            bias2[m * 4 + r] = 2.8853900817779268f * (b_ih[hid] + b_hh[hid]);
        }

    #define SL(s, l, u_) ((((s) * (LAYERS - 1) + (l)) * U + (u_)) * 1024)
    const int off = g * 256 + bc * 16;

    uint4  cur[U];
    float4 eraw[U][2];
    int4   tok_pf;
    const int* xp = x + (bbase + bc) * SEQ;
    if (w == 0) {
        const int4 t4 = *(const int4*)(xp);
        const int tk[U] = {t4.x, t4.y, t4.z, t4.w};
        #pragma unroll
        for (int u = 0; u < U; ++u) {
            const float4* ep = (const float4*)(emb + tk[u] * EMBED + g * 8);
            const float4 e0 = ep[0], e1 = ep[1];
            cur[u] = uint4{pk(e0.x, e0.y), pk(e0.z, e0.w), pk(e1.x, e1.y), pk(e1.z, e1.w)};
        }
        tok_pf = *(const int4*)(xp + U);
    }

    uint4 bown = uint4{0, 0, 0, 0};
    const f32x4 z = {0.f, 0.f, 0.f, 0.f};

    __syncthreads();

    auto body = [&](int it, int S) {
        const int tb = (it - w) * U;
        if (tb >= 0 && tb < SEQ) {
            if (w > 0)
                while (PROG(w - 1) < it) __builtin_amdgcn_s_sleep(1);
            if (w < LAYERS - 1)
                while (PROG(w + 1) < it - 2) __builtin_amdgcn_s_sleep(1);
            asm volatile("" ::: "memory");

            const bool pf = (w == 0) && (tb + U < SEQ);
            if (pf) {
                const int tk[U] = {tok_pf.x, tok_pf.y, tok_pf.z, tok_pf.w};
                #pragma unroll
                for (int u = 0; u < U; ++u) {
                    const float4* ep = (const float4*)(emb + tk[u] * EMBED + g * 8);
                    eraw[u][0] = ep[0]; eraw[u][1] = ep[1];
                }
                if (tb + 2 * U < SEQ)
                    tok_pf = *(const int4*)(xp + tb + 2 * U);
            }

            uint4 bin[U];
            if (w == 0) {
                #pragma unroll
                for (int u = 0; u < U; ++u) bin[u] = cur[u];
            } else {
                #pragma unroll
                for (int u = 0; u < U; ++u)
                    bin[u] = *(const uint4*)(hb + SL((S + 3) & 3, w - 1, u) + off);
            }
            f32x4 cin0[U], cin1[U];
            #pragma unroll
            for (int u = 0; u < U; ++u) {
                cin0[u] = __builtin_amdgcn_mfma_f32_16x16x32_f16(u2f(wf00), u2f(bin[u]), z, 0, 0, 0);
                cin1[u] = __builtin_amdgcn_mfma_f32_16x16x32_f16(u2f(wf10), u2f(bin[u]), z, 0, 0, 0);
            }
            #pragma unroll
            for (int u = 0; u < U; ++u) {
                const f32x4 c0 = __builtin_amdgcn_mfma_f32_16x16x32_f16(u2f(wf01), u2f(bown), cin0[u], 0, 0, 0);
                const f32x4 c1 = __builtin_amdgcn_mfma_f32_16x16x32_f16(u2f(wf11), u2f(bown), cin1[u], 0, 0, 0);
                float hv[8];
                #pragma unroll
                for (int r = 0; r < 4; ++r) {
                    hv[r]     = th(c0[r], bias2[r]);
                    hv[4 + r] = th(c1[r], bias2[4 + r]);
                }
                bown = uint4{pk(hv[0], hv[1]), pk(hv[2], hv[3]),
                             pk(hv[4], hv[5]), pk(hv[6], hv[7])};
                if (w < LAYERS - 1)
                    *(uint4*)(hb + SL(S, w, u) + off) = bown;
            }
            asm volatile("s_waitcnt lgkmcnt(0)" ::: "memory");
            if (lane == 0) PROG(w) = it + 1;
            if (pf) {
                #pragma unroll
                for (int u = 0; u < U; ++u) {
                    const float4 e0 = eraw[u][0], e1 = eraw[u][1];
                    cur[u] = uint4{pk(e0.x, e0.y), pk(e0.z, e0.w), pk(e1.x, e1.y), pk(e1.z, e1.w)};
                }
            }
        } else {
            if (lane == 0) PROG(w) = it + 1;
        }
    };

    for (int it = 0; it < NB; it += 4) {
        body(it + 0, 0);
        body(it + 1, 1);
        body(it + 2, 2);
        body(it + 3, 3);
    }
    #undef SL

    if (w == LAYERS - 1) *(uint4*)(fcs + off) = bown;
    __syncthreads();
    const uint4 bfc = *(const uint4*)(fcs + off);
    #pragma unroll
    for (int rep = 0; rep < 2; ++rep) {
        const int vt = w + rep * LAYERS;
        if (vt < VOCABSZ / 16) {
            const uint4 afc = mk_kp(W_fc + (vt * 16 + bc) * HIDDEN, g);
            const f32x4 c = __builtin_amdgcn_mfma_f32_16x16x32_f16(u2f(afc), u2f(bfc), z, 0, 0, 0);
            const float4 b4 = *(const float4*)(b_fc + vt * 16 + 4 * g);
            const float4 o  = {c[0] + b4.x, c[1] + b4.y, c[2] + b4.z, c[3] + b4.w};
            *(float4*)(out + (bbase + bc) * VOCABSZ + vt * 16 + 4 * g) = o;
        }
    }
    #undef PROG
}

extern "C" void kernel_launch(void* const* d_in, const int* in_sizes, int n_in,
                              void* d_out, int out_size, void* d_ws, size_t ws_size,
                              hipStream_t stream) {
    const int*   x    = (const int*)d_in[0];
    const float* emb  = (const float*)d_in[1];
    const float* W_ih = (const float*)d_in[2];
    const float* W_hh = (const float*)d_in[3];
    const float* b_ih = (const float*)d_in[4];
    const float* b_hh = (const float*)d_in[5];
    const float* W_fc = (const float*)d_in[6];
    const float* b_fc = (const float*)d_in[7];
    float* out = (float*)d_out;

    if (ws_size >= RING_BYTES + FLAG_BYTES) {
        unsigned char* ring  = (unsigned char*)d_ws;
        int*           flags = (int*)((unsigned char*)d_ws + RING_BYTES);
        rnn_sys<<<LAYERS * NBG, 64, 0, stream>>>(x, emb, W_ih, W_hh, b_ih, b_hh,
                                                 W_fc, b_fc, out, ring, flags);
    } else {
        rnn_fused<<<BATCH / BPB, 640, 0, stream>>>(x, emb, W_ih, W_hh, b_ih, b_hh,
                                                   W_fc, b_fc, out);
    }
}